// Round 4
// baseline (1493.624 us; speedup 1.0000x reference)
//
#include <hip/hip_runtime.h>

typedef __attribute__((ext_vector_type(8))) short short8;
typedef __attribute__((ext_vector_type(4))) float f32x4;

#define DEVFN __device__ __forceinline__

constexpr float SCALE_ATTN = 0.04419417382415922f;  // 1/sqrt(512)
constexpr float NEGF = -4294967296.0f;              // -(1<<32)

DEVFN unsigned short f2bf(float f) {
  unsigned int u = __float_as_uint(f);
  u += 0x7FFFu + ((u >> 16) & 1u);   // RNE (inputs finite)
  return (unsigned short)(u >> 16);
}
DEVFN float bf2f(unsigned short h) { return __uint_as_float((unsigned)h << 16); }

DEVFN void gl_lds16(const void* g, void* l) {
  // async global->LDS, 16B/lane; LDS dest = wave-uniform base + lane*16
  __builtin_amdgcn_global_load_lds(
      (const __attribute__((address_space(1))) unsigned int*)g,
      (__attribute__((address_space(3))) unsigned int*)l, 16, 0, 0);
}

// ---------- dtype detector on Q: 1 = bf16 elements, 0 = f32 elements ----------
__global__ void k_detect_f(const unsigned int* __restrict__ q, int* __restrict__ flag) {
  int lane = threadIdx.x;
  unsigned bad = 0;
  for (int i = 0; i < 64; i++) {
    unsigned v = q[i * 64 + lane];
    unsigned h = v & 0xFFFFu;
    unsigned e = (h >> 7) & 0xFFu;
    if (h != 0u && (e < 96u || e > 150u)) bad = 1;
  }
  unsigned long long anyb = __ballot(bad != 0);
  if (lane == 0) *flag = (anyb == 0ULL) ? 1 : 0;
}

// ---------- mask element-size detector: 1, 2, or 4 bytes ----------
__global__ void k_detect_m(const unsigned int* __restrict__ m, int* __restrict__ esize) {
  int lane = threadIdx.x;
  unsigned okd = 1, okf = 1, okh = 1, okb = 1;
  for (int i = 0; i < 64; i++) {
    unsigned v = m[i * 64 + lane];
    if (v > 1u) okd = 0;
    if (v != 0u && v != 0x3F800000u) okf = 0;
    unsigned h0 = v & 0xFFFFu, h1 = v >> 16;
    if ((h0 && h0 != 0x3F80u) || (h1 && h1 != 0x3F80u)) okh = 0;
    if (v & 0xFEFEFEFEu) okb = 0;
  }
  okd = (__ballot(okd == 0) == 0ULL); okf = (__ballot(okf == 0) == 0ULL);
  okh = (__ballot(okh == 0) == 0ULL); okb = (__ballot(okb == 0) == 0ULL);
  if (lane == 0) *esize = okd ? 4 : (okf ? 4 : (okh ? 2 : 1));
}

// ---------- convert-or-copy -> bf16 ----------
__global__ void k_cvt(const void* __restrict__ src, unsigned short* __restrict__ dst,
                      const int* __restrict__ bf16flag, int n) {
  int i = (blockIdx.x * blockDim.x + threadIdx.x) * 8;
  if (i >= n) return;
  if (*bf16flag) {
    *(uint4*)(dst + i) = *(const uint4*)((const unsigned short*)src + i);
  } else {
    const float* f = (const float*)src + i;
    float4 a = *(const float4*)f, b = *(const float4*)(f + 4);
    uint4 o;
    o.x = (unsigned)f2bf(a.x) | ((unsigned)f2bf(a.y) << 16);
    o.y = (unsigned)f2bf(a.z) | ((unsigned)f2bf(a.w) << 16);
    o.z = (unsigned)f2bf(b.x) | ((unsigned)f2bf(b.y) << 16);
    o.w = (unsigned)f2bf(b.z) | ((unsigned)f2bf(b.w) << 16);
    *(uint4*)(dst + i) = o;
  }
}

// ---------- V [8192x512] -> V^T [512x8192] bf16 ----------
__global__ void k_transpose_v(const void* __restrict__ Vsrc, const int* __restrict__ bf16flag,
                              unsigned short* __restrict__ Vt) {
  __shared__ unsigned short T[64][72];
  int t = threadIdx.x;
  int rb = blockIdx.x, cb = blockIdx.y;
  int r = t >> 3, c8 = (t & 7) * 8;
  int isbf = *bf16flag;
#pragma unroll
  for (int j = 0; j < 2; j++) {
    int row = rb * 64 + j * 32 + r;
    unsigned short e[8];
    if (isbf) {
      alignas(16) unsigned short tmp[8];
      *(uint4*)tmp = *(const uint4*)((const unsigned short*)Vsrc + (size_t)row * 512 + cb * 64 + c8);
#pragma unroll
      for (int i = 0; i < 8; i++) e[i] = tmp[i];
    } else {
      const float* f = (const float*)Vsrc + (size_t)row * 512 + cb * 64 + c8;
      float4 a = *(const float4*)f, b = *(const float4*)(f + 4);
      e[0] = f2bf(a.x); e[1] = f2bf(a.y); e[2] = f2bf(a.z); e[3] = f2bf(a.w);
      e[4] = f2bf(b.x); e[5] = f2bf(b.y); e[6] = f2bf(b.z); e[7] = f2bf(b.w);
    }
#pragma unroll
    for (int i = 0; i < 8; i++) T[c8 + i][j * 32 + r] = e[i];
  }
  __syncthreads();
#pragma unroll
  for (int j = 0; j < 2; j++) {
    int vtr = cb * 64 + j * 32 + r;
    alignas(16) unsigned short o[8];
#pragma unroll
    for (int i = 0; i < 8; i++) o[i] = T[j * 32 + r][c8 + i];
    *(uint4*)(Vt + (size_t)vtr * 8192 + rb * 64 + c8) = *(const uint4*)o;
  }
}

// ---------- mask -> bit-packed [8192][128] uint64 ----------
__global__ void k_pack(const void* __restrict__ mask, const int* __restrict__ esize,
                       unsigned long long* __restrict__ bits) {
  int gid = blockIdx.x * blockDim.x + threadIdx.x;
  int wv = gid >> 6, lane = gid & 63;
  int sz = *esize;
  for (int w = wv; w < 1048576; w += 4096) {
    size_t base = (size_t)w * 64 + lane;
    bool pred;
    if (sz == 1)      pred = ((const unsigned char*)mask)[base] != 0;
    else if (sz == 2) pred = ((const unsigned short*)mask)[base] != 0;
    else              pred = ((const unsigned int*)mask)[base] != 0u;
    unsigned long long b = __ballot(pred);
    if (lane == 0) bits[w] = b;
  }
}

// ---------- fused proj GEMM (z=0: Q, z=1: K): out = A @ W^T + bias, bf16 ----------
// LDS tiles swizzled: chunk' = chunk ^ (row&7) -> per-instruction uniform bank coverage.
__global__ __launch_bounds__(256, 2) void k_proj(
    const unsigned short* __restrict__ Aq, const unsigned short* __restrict__ Wq,
    const unsigned short* __restrict__ bq, unsigned short* __restrict__ outq,
    const unsigned short* __restrict__ Ak, const unsigned short* __restrict__ Wk,
    const unsigned short* __restrict__ bk, unsigned short* __restrict__ outk) {
  const unsigned short* A = blockIdx.z ? Ak : Aq;
  const unsigned short* W = blockIdx.z ? Wk : Wq;
  const unsigned short* bias = blockIdx.z ? bk : bq;
  unsigned short* out = blockIdx.z ? outk : outq;

  __shared__ alignas(16) unsigned short As[128 * 64];
  __shared__ alignas(16) unsigned short Bs[128 * 64];
  int tid = threadIdx.x, lane = tid & 63, wave = tid >> 6;
  int wi = wave >> 1, wj = wave & 1;
  int l15 = lane & 15, l4 = lane >> 4;
  int rowbase = blockIdx.x * 128, colbase = blockIdx.y * 128;
  f32x4 acc[4][4];
#pragma unroll
  for (int i = 0; i < 4; i++)
#pragma unroll
    for (int j = 0; j < 4; j++) acc[i][j] = f32x4{0.f, 0.f, 0.f, 0.f};

  int swr = l15 & 7;  // read-side swizzle key
  for (int kb = 0; kb < 512; kb += 64) {
    __syncthreads();
#pragma unroll
    for (int t = 0; t < 4; t++) {
      int inst = wave * 4 + t;                 // 16 insts, 8 rows x 64 cols each
      int r = inst * 8 + (lane >> 3);
      int c = ((lane & 7) ^ (r & 7)) * 8;      // deposit-side inverse swizzle
      gl_lds16(A + (size_t)(rowbase + r) * 512 + kb + c, &As[inst * 512]);
      gl_lds16(W + (size_t)(colbase + r) * 512 + kb + c, &Bs[inst * 512]);
    }
    __syncthreads();
#pragma unroll
    for (int t2 = 0; t2 < 2; t2++) {
      short8 a[4], b[4];
#pragma unroll
      for (int i = 0; i < 4; i++) {
        int row = wi * 64 + i * 16 + l15;
        a[i] = *(const short8*)&As[row * 64 + (((t2 * 4 + l4) ^ swr) * 8)];
      }
#pragma unroll
      for (int j = 0; j < 4; j++) {
        int row = wj * 64 + j * 16 + l15;
        b[j] = *(const short8*)&Bs[row * 64 + (((t2 * 4 + l4) ^ swr) * 8)];
      }
#pragma unroll
      for (int i = 0; i < 4; i++)
#pragma unroll
        for (int j = 0; j < 4; j++)
          acc[i][j] = __builtin_amdgcn_mfma_f32_16x16x32_bf16(a[i], b[j], acc[i][j], 0, 0, 0);
    }
  }
#pragma unroll
  for (int j = 0; j < 4; j++) {
    int col = colbase + wj * 64 + j * 16 + l15;
    float bj = bf2f(bias[col]);
#pragma unroll
    for (int i = 0; i < 4; i++) {
      int row0 = rowbase + wi * 64 + i * 16 + l4 * 4;
#pragma unroll
      for (int r = 0; r < 4; r++)
        out[(size_t)(row0 + r) * 512 + col] = f2bf(acc[i][j][r] + bj);
    }
  }
}

// ---------- flash attention: BM=64 (4 waves), BN=64, split-K=8 ----------
// LDS: SH 64KB (K-tile 64x512, then V^T-tile 512x64), P 8KB. 72KB -> 2 blocks/CU.
// 4 barriers per iter. All LDS tiles XOR-swizzled for uniform bank coverage.
__global__ __launch_bounds__(256, 2) void k_attn(
    const unsigned short* __restrict__ Qp, const unsigned short* __restrict__ Kp,
    const unsigned short* __restrict__ Vt, const unsigned long long* __restrict__ mbits,
    float* __restrict__ Opart, float* __restrict__ mpart, float* __restrict__ lpart) {
  __shared__ alignas(16) unsigned short SH[32768];  // 64KB
  __shared__ alignas(16) unsigned short P[64 * 64]; // 8KB
  int tid = threadIdx.x, lane = tid & 63, wave = tid >> 6;
  int l15 = lane & 15, l4 = lane >> 4;
  int qb = blockIdx.x * 64;
  int split = blockIdx.y;

  // persistent Q fragments: wave's 16 rows x 512 cols (64 VGPRs)
  short8 qf[16];
  {
    int row = qb + wave * 16 + l15;
#pragma unroll
    for (int t = 0; t < 16; t++)
      qf[t] = *(const short8*)(Qp + (size_t)row * 512 + t * 32 + l4 * 8);
  }
  f32x4 o[32];
#pragma unroll
  for (int f = 0; f < 32; f++) o[f] = f32x4{0.f, 0.f, 0.f, 0.f};
  float mi[4] = {NEGF, NEGF, NEGF, NEGF};
  float li[4] = {0.f, 0.f, 0.f, 0.f};

  int swK = l15 | ((l15 & 3) << 4);               // K-tile read swizzle (6-bit chunk)
  int swP_rd = (l15 & 7) ^ ((l15 & 8) >> 2);      // P read swizzle key

  for (int it = 0; it < 16; it++) {
    int kb = split * 1024 + it * 64;
    unsigned long long mw[4];
#pragma unroll
    for (int r = 0; r < 4; r++)
      mw[r] = mbits[(size_t)(qb + wave * 16 + l4 * 4 + r) * 128 + (kb >> 6)];

    // ---- barrier A: SH/P safe to overwrite ----
    __syncthreads();
    // stage K-tile: 64 rows x 512 shorts (1KB/row), 64 insts / 4 waves
#pragma unroll
    for (int t = 0; t < 16; t++) {
      int inst = wave * 16 + t;  // row index 0..63
      int swz = (inst & 15) | ((inst & 3) << 4);
      gl_lds16(Kp + (size_t)(kb + inst) * 512 + ((lane ^ swz) * 8), &SH[inst * 512]);
    }
    __syncthreads();  // ---- barrier B: K staged ----

    // ---- S = Q K^T ----
    f32x4 sacc[4];
#pragma unroll
    for (int c = 0; c < 4; c++) sacc[c] = f32x4{0.f, 0.f, 0.f, 0.f};
#pragma unroll
    for (int t2 = 0; t2 < 16; t2++) {
      short8 a = qf[t2];
#pragma unroll
      for (int c = 0; c < 4; c++) {
        int row = c * 16 + l15;
        short8 b = *(const short8*)&SH[row * 512 + (((t2 * 4 + l4) ^ swK) * 8)];
        sacc[c] = __builtin_amdgcn_mfma_f32_16x16x32_bf16(a, b, sacc[c], 0, 0, 0);
      }
    }

    // ---- scale + mask ----
#pragma unroll
    for (int c = 0; c < 4; c++)
#pragma unroll
      for (int r = 0; r < 4; r++) {
        float s = sacc[c][r] * SCALE_ATTN;
        bool msk = (mw[r] >> (c * 16 + l15)) & 1ULL;
        sacc[c][r] = msk ? NEGF : s;
      }

    // ---- online softmax (rows wave-local; reduce over lane&15) ----
    float alpha[4], mnew[4];
#pragma unroll
    for (int r = 0; r < 4; r++) {
      float t = fmaxf(fmaxf(sacc[0][r], sacc[1][r]), fmaxf(sacc[2][r], sacc[3][r]));
#pragma unroll
      for (int off = 1; off < 16; off <<= 1) t = fmaxf(t, __shfl_xor(t, off, 64));
      float mn = fmaxf(mi[r], t);
      alpha[r] = __expf(mi[r] - mn);
      mi[r] = mn; mnew[r] = mn;
    }
#pragma unroll
    for (int c = 0; c < 4; c++)
#pragma unroll
      for (int r = 0; r < 4; r++)
        sacc[c][r] = __expf(sacc[c][r] - mnew[r]);
#pragma unroll
    for (int r = 0; r < 4; r++) {
      float t = sacc[0][r] + sacc[1][r] + sacc[2][r] + sacc[3][r];
#pragma unroll
      for (int off = 1; off < 16; off <<= 1) t += __shfl_xor(t, off, 64);
      li[r] = li[r] * alpha[r] + t;
    }

    // ---- P (C-layout) -> LDS, swizzled ----
#pragma unroll
    for (int r = 0; r < 4; r++) {
      int prow = wave * 16 + l4 * 4 + r;
      int s = (prow & 7) ^ ((prow & 8) >> 2);
#pragma unroll
      for (int c = 0; c < 4; c++) {
        int chunk = (c * 2 + (l15 >> 3)) ^ s;
        P[prow * 64 + chunk * 8 + (l15 & 7)] = f2bf(sacc[c][r]);
      }
    }
#pragma unroll
    for (int f = 0; f < 32; f++)
#pragma unroll
      for (int r = 0; r < 4; r++) o[f][r] *= alpha[r];

    __syncthreads();  // ---- barrier C: P visible, K reads done ----
    // stage V^T tile: 512 rows x 64 shorts (128B/row), 64 insts / 4 waves
#pragma unroll
    for (int t = 0; t < 16; t++) {
      int inst = wave * 16 + t;
      int vcol = inst * 8 + (lane >> 3);
      int cc = lane & 7;
      gl_lds16(Vt + (size_t)vcol * 8192 + kb + (((cc ^ (vcol & 7)) * 8)), &SH[inst * 512]);
    }
    __syncthreads();  // ---- barrier D: V staged ----

    // ---- O += P @ V ----
#pragma unroll
    for (int u = 0; u < 2; u++) {
      int prow = wave * 16 + l15;
      short8 a = *(const short8*)&P[prow * 64 + (((u * 4 + l4) ^ swP_rd) * 8)];
#pragma unroll
      for (int f = 0; f < 32; f++) {
        int vrow = f * 16 + l15;
        short8 b = *(const short8*)&SH[vrow * 64 + (((u * 4 + l4) ^ (l15 & 7)) * 8)];
        o[f] = __builtin_amdgcn_mfma_f32_16x16x32_bf16(a, b, o[f], 0, 0, 0);
      }
    }
  }

  // ---- epilogue ----
#pragma unroll
  for (int r = 0; r < 4; r++) {
    int row = qb + wave * 16 + l4 * 4 + r;
    if (l15 == 0) {
      mpart[(size_t)split * 8192 + row] = mi[r];
      lpart[(size_t)split * 8192 + row] = li[r];
    }
  }
#pragma unroll
  for (int f = 0; f < 32; f++) {
    int col = f * 16 + l15;
#pragma unroll
    for (int r = 0; r < 4; r++) {
      int row = qb + wave * 16 + l4 * 4 + r;
      Opart[((size_t)split * 8192 + row) * 512 + col] = o[f][r];
    }
  }
}

// ---------- combine 8 split-K partials -> f32 out ----------
__global__ void k_combine(const float* __restrict__ Opart, const float* __restrict__ mpart,
                          const float* __restrict__ lpart, float* __restrict__ out) {
  int gid = blockIdx.x * blockDim.x + threadIdx.x;  // 1,048,576 threads
  int row = gid >> 7;
  int c4 = (gid & 127) * 4;
  float m[8], w[8];
  float M = NEGF;
#pragma unroll
  for (int s = 0; s < 8; s++) { m[s] = mpart[s * 8192 + row]; M = fmaxf(M, m[s]); }
  float L = 0.f;
#pragma unroll
  for (int s = 0; s < 8; s++) { w[s] = __expf(m[s] - M); L += w[s] * lpart[s * 8192 + row]; }
  float inv = 1.0f / L;
  float4 res = {0.f, 0.f, 0.f, 0.f};
#pragma unroll
  for (int s = 0; s < 8; s++) {
    float4 a = *(const float4*)(Opart + (size_t)s * 4194304 + (size_t)row * 512 + c4);
    res.x += w[s] * a.x; res.y += w[s] * a.y; res.z += w[s] * a.z; res.w += w[s] * a.w;
  }
  res.x *= inv; res.y *= inv; res.z *= inv; res.w *= inv;
  *(float4*)(out + (size_t)row * 512 + c4) = res;
}

extern "C" void kernel_launch(void* const* d_in, const int* in_sizes, int n_in,
                              void* d_out, int out_size, void* d_ws, size_t ws_size,
                              hipStream_t stream) {
  const void* Q   = d_in[0];
  const void* K   = d_in[1];
  const void* V   = d_in[2];
  const void* WQw = d_in[3];
  const void* WQb = d_in[4];
  const void* WKw = d_in[5];
  const void* WKb = d_in[6];
  const void* mask = d_in[7];
  float* out = (float*)d_out;
  char* ws = (char*)d_ws;
  (void)in_sizes; (void)n_in; (void)out_size; (void)ws_size;

  constexpr size_t SZ_MAT = (size_t)8192 * 512 * 2;  // 8 MB bf16
  size_t off = 4096;
  unsigned short* Qb  = (unsigned short*)(ws + off); off += SZ_MAT;
  unsigned short* Kb  = (unsigned short*)(ws + off); off += SZ_MAT;
  unsigned short* Wqb = (unsigned short*)(ws + off); off += (size_t)512 * 512 * 2;
  unsigned short* Wkb = (unsigned short*)(ws + off); off += (size_t)512 * 512 * 2;
  unsigned short* bqb = (unsigned short*)(ws + off); off += 1024;
  unsigned short* bkb = (unsigned short*)(ws + off); off += 1024;
  unsigned short* Vt  = (unsigned short*)(ws + off); off += SZ_MAT;
  unsigned short* Qp  = (unsigned short*)(ws + off); off += SZ_MAT;
  unsigned short* Kp  = (unsigned short*)(ws + off); off += SZ_MAT;
  unsigned long long* mbits = (unsigned long long*)(ws + off); off += (size_t)8192 * 128 * 8;
  float* Opart = (float*)(ws + off); off += (size_t)8 * 8192 * 512 * 4;  // 128 MB
  float* mpart = (float*)(ws + off); off += (size_t)8 * 8192 * 4;
  float* lpart = (float*)(ws + off); off += (size_t)8 * 8192 * 4;
  int* fflag = (int*)ws;
  int* esize = (int*)(ws + 64);

  k_detect_f<<<1, 64, 0, stream>>>((const unsigned int*)Q, fflag);
  k_detect_m<<<1, 64, 0, stream>>>((const unsigned int*)mask, esize);
  k_cvt<<<2048, 256, 0, stream>>>(Q, Qb, fflag, 8192 * 512);
  k_cvt<<<2048, 256, 0, stream>>>(K, Kb, fflag, 8192 * 512);
  k_cvt<<<128, 256, 0, stream>>>(WQw, Wqb, fflag, 512 * 512);
  k_cvt<<<128, 256, 0, stream>>>(WKw, Wkb, fflag, 512 * 512);
  k_cvt<<<1, 64, 0, stream>>>(WQb, bqb, fflag, 512);
  k_cvt<<<1, 64, 0, stream>>>(WKb, bkb, fflag, 512);
  k_transpose_v<<<dim3(128, 8), 256, 0, stream>>>(V, fflag, Vt);
  k_pack<<<1024, 256, 0, stream>>>(mask, esize, mbits);
  k_proj<<<dim3(64, 4, 2), 256, 0, stream>>>(Qb, Wqb, bqb, Qp, Kb, Wkb, bkb, Kp);
  k_attn<<<dim3(128, 8), 256, 0, stream>>>(Qp, Kp, Vt, mbits, Opart, mpart, lpart);
  k_combine<<<4096, 256, 0, stream>>>(Opart, mpart, lpart, out);
}

// Round 5
// 1464.318 us; speedup vs baseline: 1.0200x; 1.0200x over previous
//
#include <hip/hip_runtime.h>

typedef __attribute__((ext_vector_type(8))) short short8;
typedef __attribute__((ext_vector_type(4))) float f32x4;

#define DEVFN __device__ __forceinline__

constexpr float SCALE_ATTN = 0.04419417382415922f;  // 1/sqrt(512)
constexpr float NEGF = -4294967296.0f;              // -(1<<32)

DEVFN unsigned short f2bf(float f) {
  unsigned int u = __float_as_uint(f);
  u += 0x7FFFu + ((u >> 16) & 1u);   // RNE (inputs finite)
  return (unsigned short)(u >> 16);
}
DEVFN float bf2f(unsigned short h) { return __uint_as_float((unsigned)h << 16); }

DEVFN void gl_lds16(const void* g, void* l) {
  // async global->LDS, 16B/lane; LDS dest = wave-uniform base + lane*16
  __builtin_amdgcn_global_load_lds(
      (const __attribute__((address_space(1))) unsigned int*)g,
      (__attribute__((address_space(3))) unsigned int*)l, 16, 0, 0);
}

// ---------- dtype detector on Q: 1 = bf16 elements, 0 = f32 elements ----------
__global__ void k_detect_f(const unsigned int* __restrict__ q, int* __restrict__ flag) {
  int lane = threadIdx.x;
  unsigned bad = 0;
  for (int i = 0; i < 64; i++) {
    unsigned v = q[i * 64 + lane];
    unsigned h = v & 0xFFFFu;
    unsigned e = (h >> 7) & 0xFFu;
    if (h != 0u && (e < 96u || e > 150u)) bad = 1;
  }
  unsigned long long anyb = __ballot(bad != 0);
  if (lane == 0) *flag = (anyb == 0ULL) ? 1 : 0;
}

// ---------- mask element-size detector: 1, 2, or 4 bytes ----------
__global__ void k_detect_m(const unsigned int* __restrict__ m, int* __restrict__ esize) {
  int lane = threadIdx.x;
  unsigned okd = 1, okf = 1, okh = 1, okb = 1;
  for (int i = 0; i < 64; i++) {
    unsigned v = m[i * 64 + lane];
    if (v > 1u) okd = 0;
    if (v != 0u && v != 0x3F800000u) okf = 0;
    unsigned h0 = v & 0xFFFFu, h1 = v >> 16;
    if ((h0 && h0 != 0x3F80u) || (h1 && h1 != 0x3F80u)) okh = 0;
    if (v & 0xFEFEFEFEu) okb = 0;
  }
  okd = (__ballot(okd == 0) == 0ULL); okf = (__ballot(okf == 0) == 0ULL);
  okh = (__ballot(okh == 0) == 0ULL); okb = (__ballot(okb == 0) == 0ULL);
  if (lane == 0) *esize = okd ? 4 : (okf ? 4 : (okh ? 2 : 1));
}

// ---------- convert-or-copy -> bf16 ----------
__global__ void k_cvt(const void* __restrict__ src, unsigned short* __restrict__ dst,
                      const int* __restrict__ bf16flag, int n) {
  int i = (blockIdx.x * blockDim.x + threadIdx.x) * 8;
  if (i >= n) return;
  if (*bf16flag) {
    *(uint4*)(dst + i) = *(const uint4*)((const unsigned short*)src + i);
  } else {
    const float* f = (const float*)src + i;
    float4 a = *(const float4*)f, b = *(const float4*)(f + 4);
    uint4 o;
    o.x = (unsigned)f2bf(a.x) | ((unsigned)f2bf(a.y) << 16);
    o.y = (unsigned)f2bf(a.z) | ((unsigned)f2bf(a.w) << 16);
    o.z = (unsigned)f2bf(b.x) | ((unsigned)f2bf(b.y) << 16);
    o.w = (unsigned)f2bf(b.z) | ((unsigned)f2bf(b.w) << 16);
    *(uint4*)(dst + i) = o;
  }
}

// ---------- V [8192x512] -> V^T [512x8192] bf16 ----------
__global__ void k_transpose_v(const void* __restrict__ Vsrc, const int* __restrict__ bf16flag,
                              unsigned short* __restrict__ Vt) {
  __shared__ unsigned short T[64][72];
  int t = threadIdx.x;
  int rb = blockIdx.x, cb = blockIdx.y;
  int r = t >> 3, c8 = (t & 7) * 8;
  int isbf = *bf16flag;
#pragma unroll
  for (int j = 0; j < 2; j++) {
    int row = rb * 64 + j * 32 + r;
    unsigned short e[8];
    if (isbf) {
      alignas(16) unsigned short tmp[8];
      *(uint4*)tmp = *(const uint4*)((const unsigned short*)Vsrc + (size_t)row * 512 + cb * 64 + c8);
#pragma unroll
      for (int i = 0; i < 8; i++) e[i] = tmp[i];
    } else {
      const float* f = (const float*)Vsrc + (size_t)row * 512 + cb * 64 + c8;
      float4 a = *(const float4*)f, b = *(const float4*)(f + 4);
      e[0] = f2bf(a.x); e[1] = f2bf(a.y); e[2] = f2bf(a.z); e[3] = f2bf(a.w);
      e[4] = f2bf(b.x); e[5] = f2bf(b.y); e[6] = f2bf(b.z); e[7] = f2bf(b.w);
    }
#pragma unroll
    for (int i = 0; i < 8; i++) T[c8 + i][j * 32 + r] = e[i];
  }
  __syncthreads();
#pragma unroll
  for (int j = 0; j < 2; j++) {
    int vtr = cb * 64 + j * 32 + r;
    alignas(16) unsigned short o[8];
#pragma unroll
    for (int i = 0; i < 8; i++) o[i] = T[j * 32 + r][c8 + i];
    *(uint4*)(Vt + (size_t)vtr * 8192 + rb * 64 + c8) = *(const uint4*)o;
  }
}

// ---------- mask -> bit-packed [8192][128] uint64, vectorized 16B/lane ----------
DEVFN unsigned nib4(unsigned v) {       // 4 bytes -> 4 bits (b!=0)
  unsigned t = v; t |= t >> 1; t |= t >> 2; t |= t >> 4; t &= 0x01010101u;
  return (t * 0x10204080u) >> 28;
}
DEVFN unsigned pair2(unsigned v) {      // 2 shorts -> 2 bits
  unsigned t = v; t |= t >> 8; t |= t >> 4; t |= t >> 2; t |= t >> 1;
  return (t & 1u) | (((t >> 16) & 1u) << 1);
}
__global__ void k_pack(const void* __restrict__ mask, const int* __restrict__ esize,
                       unsigned long long* __restrict__ bits) {
  int wv = (blockIdx.x * blockDim.x + threadIdx.x) >> 6;  // 4096 waves
  int lane = threadIdx.x & 63;
  int sz = *esize;
  const uint4* m = (const uint4*)mask;
  if (sz == 4) {
    for (int g = wv; g < 262144; g += 4096) {           // 256 elems/wave-iter
      uint4 v = m[(size_t)g * 64 + lane];
      unsigned nib = (v.x != 0u) | ((v.y != 0u) << 1) | ((v.z != 0u) << 2) | ((v.w != 0u) << 3);
      unsigned long long x = (unsigned long long)nib << ((lane & 15) * 4);
      x |= __shfl_xor(x, 1); x |= __shfl_xor(x, 2);
      x |= __shfl_xor(x, 4); x |= __shfl_xor(x, 8);
      if ((lane & 15) == 0) bits[g * 4 + (lane >> 4)] = x;
    }
  } else if (sz == 2) {
    for (int g = wv; g < 32768; g += 4096) {            // 512 elems/wave-iter
      uint4 v = m[(size_t)g * 64 + lane];
      unsigned c8 = pair2(v.x) | (pair2(v.y) << 2) | (pair2(v.z) << 4) | (pair2(v.w) << 6);
      unsigned long long x = (unsigned long long)c8 << ((lane & 7) * 8);
      x |= __shfl_xor(x, 1); x |= __shfl_xor(x, 2); x |= __shfl_xor(x, 4);
      if ((lane & 7) == 0) bits[g * 8 + (lane >> 3)] = x;
    }
  } else {
    for (int g = wv; g < 16384; g += 4096) {            // 1024 elems/wave-iter
      uint4 v = m[(size_t)g * 64 + lane];
      unsigned c16 = nib4(v.x) | (nib4(v.y) << 4) | (nib4(v.z) << 8) | (nib4(v.w) << 12);
      unsigned long long x = (unsigned long long)c16 << ((lane & 3) * 16);
      x |= __shfl_xor(x, 1); x |= __shfl_xor(x, 2);
      if ((lane & 3) == 0) bits[g * 16 + (lane >> 2)] = x;
    }
  }
}

// ---------- fused proj GEMM (z=0: Q, z=1: K): out = A @ W^T + bias, bf16 ----------
__global__ __launch_bounds__(256, 2) void k_proj(
    const unsigned short* __restrict__ Aq, const unsigned short* __restrict__ Wq,
    const unsigned short* __restrict__ bq, unsigned short* __restrict__ outq,
    const unsigned short* __restrict__ Ak, const unsigned short* __restrict__ Wk,
    const unsigned short* __restrict__ bk, unsigned short* __restrict__ outk) {
  const unsigned short* A = blockIdx.z ? Ak : Aq;
  const unsigned short* W = blockIdx.z ? Wk : Wq;
  const unsigned short* bias = blockIdx.z ? bk : bq;
  unsigned short* out = blockIdx.z ? outk : outq;

  __shared__ alignas(16) unsigned short As[128 * 64];
  __shared__ alignas(16) unsigned short Bs[128 * 64];
  int tid = threadIdx.x, lane = tid & 63, wave = tid >> 6;
  int wi = wave >> 1, wj = wave & 1;
  int l15 = lane & 15, l4 = lane >> 4;
  int rowbase = blockIdx.x * 128, colbase = blockIdx.y * 128;
  f32x4 acc[4][4];
#pragma unroll
  for (int i = 0; i < 4; i++)
#pragma unroll
    for (int j = 0; j < 4; j++) acc[i][j] = f32x4{0.f, 0.f, 0.f, 0.f};

  int swr = l15 & 7;
  for (int kb = 0; kb < 512; kb += 64) {
    __syncthreads();
#pragma unroll
    for (int t = 0; t < 4; t++) {
      int inst = wave * 4 + t;
      int r = inst * 8 + (lane >> 3);
      int c = ((lane & 7) ^ (r & 7)) * 8;
      gl_lds16(A + (size_t)(rowbase + r) * 512 + kb + c, &As[inst * 512]);
      gl_lds16(W + (size_t)(colbase + r) * 512 + kb + c, &Bs[inst * 512]);
    }
    __syncthreads();
#pragma unroll
    for (int t2 = 0; t2 < 2; t2++) {
      short8 a[4], b[4];
#pragma unroll
      for (int i = 0; i < 4; i++) {
        int row = wi * 64 + i * 16 + l15;
        a[i] = *(const short8*)&As[row * 64 + (((t2 * 4 + l4) ^ swr) * 8)];
      }
#pragma unroll
      for (int j = 0; j < 4; j++) {
        int row = wj * 64 + j * 16 + l15;
        b[j] = *(const short8*)&Bs[row * 64 + (((t2 * 4 + l4) ^ swr) * 8)];
      }
#pragma unroll
      for (int i = 0; i < 4; i++)
#pragma unroll
        for (int j = 0; j < 4; j++)
          acc[i][j] = __builtin_amdgcn_mfma_f32_16x16x32_bf16(a[i], b[j], acc[i][j], 0, 0, 0);
    }
  }
#pragma unroll
  for (int j = 0; j < 4; j++) {
    int col = colbase + wj * 64 + j * 16 + l15;
    float bj = bf2f(bias[col]);
#pragma unroll
    for (int i = 0; i < 4; i++) {
      int row0 = rowbase + wi * 64 + i * 16 + l4 * 4;
#pragma unroll
      for (int r = 0; r < 4; r++)
        out[(size_t)(row0 + r) * 512 + col] = f2bf(acc[i][j][r] + bj);
    }
  }
}

// ---------- flash attention: BM=64 (4 waves), BN=64, split-K=8, XCD-pinned ----------
// b = blockIdx.x (0..1023): split = b&7 (== XCD under round-robin), qb = (b>>3)*64.
// Per-XCD hot set: K-split 1MB + V-split 1MB -> L2-resident.
// Opart: bf16, fragment-native coalesced: uint2 at ((b*256+tid)*32+f).
__global__ __launch_bounds__(256, 2) void k_attn(
    const unsigned short* __restrict__ Qp, const unsigned short* __restrict__ Kp,
    const unsigned short* __restrict__ Vt, const unsigned long long* __restrict__ mbits,
    unsigned short* __restrict__ Opart, float* __restrict__ mpart, float* __restrict__ lpart) {
  __shared__ alignas(16) unsigned short SH[32768];  // 64KB: K-tile 64x512 | V^T-tile 512x64
  __shared__ alignas(16) unsigned short P[64 * 64]; // 8KB
  int tid = threadIdx.x, lane = tid & 63, wave = tid >> 6;
  int l15 = lane & 15, l4 = lane >> 4;
  int b = blockIdx.x;
  int split = b & 7;
  int qb = (b >> 3) * 64;

  short8 qf[16];  // persistent Q fragments (wave's 16 rows x 512 cols)
  {
    int row = qb + wave * 16 + l15;
#pragma unroll
    for (int t = 0; t < 16; t++)
      qf[t] = *(const short8*)(Qp + (size_t)row * 512 + t * 32 + l4 * 8);
  }
  f32x4 o[32];
#pragma unroll
  for (int f = 0; f < 32; f++) o[f] = f32x4{0.f, 0.f, 0.f, 0.f};
  float mi[4] = {NEGF, NEGF, NEGF, NEGF};
  float li[4] = {0.f, 0.f, 0.f, 0.f};

  int swK = l15 | ((l15 & 3) << 4);
  int swP_rd = (l15 & 7) ^ ((l15 & 8) >> 2);

  for (int it = 0; it < 16; it++) {
    int kb = split * 1024 + it * 64;
    unsigned long long mw[4];
#pragma unroll
    for (int r = 0; r < 4; r++)
      mw[r] = mbits[(size_t)(qb + wave * 16 + l4 * 4 + r) * 128 + split * 16 + it];

    __syncthreads();  // A: SH safe to overwrite
#pragma unroll
    for (int t = 0; t < 16; t++) {
      int inst = wave * 16 + t;  // K row 0..63
      int swz = (inst & 15) | ((inst & 3) << 4);
      gl_lds16(Kp + (size_t)(kb + inst) * 512 + ((lane ^ swz) * 8), &SH[inst * 512]);
    }
    __syncthreads();  // B: K staged

    f32x4 sacc[4];
#pragma unroll
    for (int c = 0; c < 4; c++) sacc[c] = f32x4{0.f, 0.f, 0.f, 0.f};
#pragma unroll
    for (int t2 = 0; t2 < 16; t2++) {
      short8 a = qf[t2];
#pragma unroll
      for (int c = 0; c < 4; c++) {
        int row = c * 16 + l15;
        short8 bb = *(const short8*)&SH[row * 512 + (((t2 * 4 + l4) ^ swK) * 8)];
        sacc[c] = __builtin_amdgcn_mfma_f32_16x16x32_bf16(a, bb, sacc[c], 0, 0, 0);
      }
    }

#pragma unroll
    for (int c = 0; c < 4; c++)
#pragma unroll
      for (int r = 0; r < 4; r++) {
        float s = sacc[c][r] * SCALE_ATTN;
        bool msk = (mw[r] >> (c * 16 + l15)) & 1ULL;
        sacc[c][r] = msk ? NEGF : s;
      }

    float alpha[4], mnew[4];
#pragma unroll
    for (int r = 0; r < 4; r++) {
      float t = fmaxf(fmaxf(sacc[0][r], sacc[1][r]), fmaxf(sacc[2][r], sacc[3][r]));
#pragma unroll
      for (int off = 1; off < 16; off <<= 1) t = fmaxf(t, __shfl_xor(t, off, 64));
      float mn = fmaxf(mi[r], t);
      alpha[r] = __expf(mi[r] - mn);
      mi[r] = mn; mnew[r] = mn;
    }
#pragma unroll
    for (int c = 0; c < 4; c++)
#pragma unroll
      for (int r = 0; r < 4; r++)
        sacc[c][r] = __expf(sacc[c][r] - mnew[r]);
#pragma unroll
    for (int r = 0; r < 4; r++) {
      float t = sacc[0][r] + sacc[1][r] + sacc[2][r] + sacc[3][r];
#pragma unroll
      for (int off = 1; off < 16; off <<= 1) t += __shfl_xor(t, off, 64);
      li[r] = li[r] * alpha[r] + t;
    }

#pragma unroll
    for (int r = 0; r < 4; r++) {
      int prow = wave * 16 + l4 * 4 + r;
      int s = (prow & 7) ^ ((prow & 8) >> 2);
#pragma unroll
      for (int c = 0; c < 4; c++) {
        int chunk = (c * 2 + (l15 >> 3)) ^ s;
        P[prow * 64 + chunk * 8 + (l15 & 7)] = f2bf(sacc[c][r]);
      }
    }
#pragma unroll
    for (int f = 0; f < 32; f++)
#pragma unroll
      for (int r = 0; r < 4; r++) o[f][r] *= alpha[r];

    __syncthreads();  // C: P visible, K reads done
#pragma unroll
    for (int t = 0; t < 16; t++) {
      int inst = wave * 16 + t;
      int vcol = inst * 8 + (lane >> 3);
      int cc = lane & 7;
      gl_lds16(Vt + (size_t)vcol * 8192 + kb + (((cc ^ (vcol & 7)) * 8)), &SH[inst * 512]);
    }
    __syncthreads();  // D: V staged

#pragma unroll
    for (int u = 0; u < 2; u++) {
      int prow = wave * 16 + l15;
      short8 a = *(const short8*)&P[prow * 64 + (((u * 4 + l4) ^ swP_rd) * 8)];
#pragma unroll
      for (int f = 0; f < 32; f++) {
        int vrow = f * 16 + l15;
        short8 bb = *(const short8*)&SH[vrow * 64 + (((u * 4 + l4) ^ (l15 & 7)) * 8)];
        o[f] = __builtin_amdgcn_mfma_f32_16x16x32_bf16(a, bb, o[f], 0, 0, 0);
      }
    }
  }

  // ---- epilogue: m/l + fragment-native bf16 partials ----
#pragma unroll
  for (int r = 0; r < 4; r++) {
    int row = qb + wave * 16 + l4 * 4 + r;
    if (l15 == 0) {
      mpart[(size_t)split * 8192 + row] = mi[r];
      lpart[(size_t)split * 8192 + row] = li[r];
    }
  }
  uint2* op = (uint2*)Opart + ((size_t)b * 256 + tid) * 32;
#pragma unroll
  for (int f = 0; f < 32; f++) {
    uint2 v;
    v.x = (unsigned)f2bf(o[f][0]) | ((unsigned)f2bf(o[f][1]) << 16);
    v.y = (unsigned)f2bf(o[f][2]) | ((unsigned)f2bf(o[f][3]) << 16);
    op[f] = v;
  }
}

// ---------- combine 8 split-K partials (fragment-native bf16) -> f32 out ----------
__global__ void k_combine(const unsigned short* __restrict__ Opart,
                          const float* __restrict__ mpart, const float* __restrict__ lpart,
                          float* __restrict__ out) {
  int q = blockIdx.x;                 // 0..127 (qb tile)
  int half = blockIdx.y;              // 0..1 (f range)
  int tid = threadIdx.x;
  int wave = tid >> 6, l4 = (tid >> 4) & 3, l15 = tid & 15;
  int row0 = q * 64 + wave * 16 + l4 * 4;

  float w[8][4], inv[4];
#pragma unroll
  for (int r = 0; r < 4; r++) {
    float M = NEGF;
    float mv[8];
#pragma unroll
    for (int s = 0; s < 8; s++) { mv[s] = mpart[s * 8192 + row0 + r]; M = fmaxf(M, mv[s]); }
    float L = 0.f;
#pragma unroll
    for (int s = 0; s < 8; s++) {
      float ws = __expf(mv[s] - M);
      w[s][r] = ws;
      L += ws * lpart[s * 8192 + row0 + r];
    }
    inv[r] = 1.0f / L;
  }
#pragma unroll
  for (int fo = 0; fo < 16; fo++) {
    int f = half * 16 + fo;
    float acc[4] = {0.f, 0.f, 0.f, 0.f};
#pragma unroll
    for (int s = 0; s < 8; s++) {
      const uint2* op = (const uint2*)Opart + ((size_t)(q * 8 + s) * 256 + tid) * 32;
      uint2 v = op[f];
      acc[0] += w[s][0] * bf2f((unsigned short)(v.x & 0xFFFFu));
      acc[1] += w[s][1] * bf2f((unsigned short)(v.x >> 16));
      acc[2] += w[s][2] * bf2f((unsigned short)(v.y & 0xFFFFu));
      acc[3] += w[s][3] * bf2f((unsigned short)(v.y >> 16));
    }
    int col = f * 16 + l15;
#pragma unroll
    for (int r = 0; r < 4; r++)
      out[(size_t)(row0 + r) * 512 + col] = acc[r] * inv[r];
  }
}

extern "C" void kernel_launch(void* const* d_in, const int* in_sizes, int n_in,
                              void* d_out, int out_size, void* d_ws, size_t ws_size,
                              hipStream_t stream) {
  const void* Q   = d_in[0];
  const void* K   = d_in[1];
  const void* V   = d_in[2];
  const void* WQw = d_in[3];
  const void* WQb = d_in[4];
  const void* WKw = d_in[5];
  const void* WKb = d_in[6];
  const void* mask = d_in[7];
  float* out = (float*)d_out;
  char* ws = (char*)d_ws;
  (void)in_sizes; (void)n_in; (void)out_size; (void)ws_size;

  constexpr size_t SZ_MAT = (size_t)8192 * 512 * 2;  // 8 MB bf16
  size_t off = 4096;
  unsigned short* Qb  = (unsigned short*)(ws + off); off += SZ_MAT;
  unsigned short* Kb  = (unsigned short*)(ws + off); off += SZ_MAT;
  unsigned short* Wqb = (unsigned short*)(ws + off); off += (size_t)512 * 512 * 2;
  unsigned short* Wkb = (unsigned short*)(ws + off); off += (size_t)512 * 512 * 2;
  unsigned short* bqb = (unsigned short*)(ws + off); off += 1024;
  unsigned short* bkb = (unsigned short*)(ws + off); off += 1024;
  unsigned short* Vt  = (unsigned short*)(ws + off); off += SZ_MAT;
  unsigned short* Qp  = (unsigned short*)(ws + off); off += SZ_MAT;
  unsigned short* Kp  = (unsigned short*)(ws + off); off += SZ_MAT;
  unsigned long long* mbits = (unsigned long long*)(ws + off); off += (size_t)8192 * 128 * 8;
  unsigned short* Opart = (unsigned short*)(ws + off); off += (size_t)1024 * 256 * 32 * 8;  // 64 MB
  float* mpart = (float*)(ws + off); off += (size_t)8 * 8192 * 4;
  float* lpart = (float*)(ws + off); off += (size_t)8 * 8192 * 4;
  int* fflag = (int*)ws;
  int* esize = (int*)(ws + 64);

  k_detect_f<<<1, 64, 0, stream>>>((const unsigned int*)Q, fflag);
  k_detect_m<<<1, 64, 0, stream>>>((const unsigned int*)mask, esize);
  k_cvt<<<2048, 256, 0, stream>>>(Q, Qb, fflag, 8192 * 512);
  k_cvt<<<2048, 256, 0, stream>>>(K, Kb, fflag, 8192 * 512);
  k_cvt<<<128, 256, 0, stream>>>(WQw, Wqb, fflag, 512 * 512);
  k_cvt<<<128, 256, 0, stream>>>(WKw, Wkb, fflag, 512 * 512);
  k_cvt<<<1, 64, 0, stream>>>(WQb, bqb, fflag, 512);
  k_cvt<<<1, 64, 0, stream>>>(WKb, bkb, fflag, 512);
  k_transpose_v<<<dim3(128, 8), 256, 0, stream>>>(V, fflag, Vt);
  k_pack<<<1024, 256, 0, stream>>>(mask, esize, mbits);
  k_proj<<<dim3(64, 4, 2), 256, 0, stream>>>(Qb, Wqb, bqb, Qp, Kb, Wkb, bkb, Kp);
  k_attn<<<1024, 256, 0, stream>>>(Qp, Kp, Vt, mbits, Opart, mpart, lpart);
  k_combine<<<dim3(128, 2), 256, 0, stream>>>(Opart, mpart, lpart, out);
}

// Round 6
// 1347.407 us; speedup vs baseline: 1.1085x; 1.0868x over previous
//
#include <hip/hip_runtime.h>

typedef __attribute__((ext_vector_type(8))) short short8;
typedef __attribute__((ext_vector_type(4))) float f32x4;

#define DEVFN __device__ __forceinline__

constexpr float SCALE_ATTN = 0.04419417382415922f;  // 1/sqrt(512)
constexpr float NEGF = -4294967296.0f;              // -(1<<32)

DEVFN unsigned short f2bf(float f) {
  unsigned int u = __float_as_uint(f);
  u += 0x7FFFu + ((u >> 16) & 1u);   // RNE (inputs finite)
  return (unsigned short)(u >> 16);
}
DEVFN float bf2f(unsigned short h) { return __uint_as_float((unsigned)h << 16); }

DEVFN void gl_lds16(const void* g, void* l) {
  __builtin_amdgcn_global_load_lds(
      (const __attribute__((address_space(1))) unsigned int*)g,
      (__attribute__((address_space(3))) unsigned int*)l, 16, 0, 0);
}

// ---------- merged detectors: block 0 = Q dtype, block 1 = mask esize ----------
__global__ void k_detect(const unsigned int* __restrict__ q, const unsigned int* __restrict__ m,
                         int* __restrict__ fflag, int* __restrict__ esize) {
  int lane = threadIdx.x;
  if (blockIdx.x == 0) {
    unsigned bad = 0;
    for (int i = 0; i < 64; i++) {
      unsigned v = q[i * 64 + lane];
      unsigned h = v & 0xFFFFu;
      unsigned e = (h >> 7) & 0xFFu;
      if (h != 0u && (e < 96u || e > 150u)) bad = 1;
    }
    unsigned long long anyb = __ballot(bad != 0);
    if (lane == 0) *fflag = (anyb == 0ULL) ? 1 : 0;
  } else {
    unsigned okd = 1, okh = 1, okb = 1;
    for (int i = 0; i < 64; i++) {
      unsigned v = m[i * 64 + lane];
      if (v > 1u && v != 0x3F800000u) okd = 0;   // int32/f32 0|1|1.0f
      unsigned h0 = v & 0xFFFFu, h1 = v >> 16;
      if ((h0 && h0 != 0x3F80u && h0 != 1u) || (h1 && h1 != 0x3F80u && h1 != 1u)) okh = 0;
      if (v & 0xFEFEFEFEu) okb = 0;
    }
    okd = (__ballot(okd == 0) == 0ULL);
    okh = (__ballot(okh == 0) == 0ULL);
    okb = (__ballot(okb == 0) == 0ULL);
    if (lane == 0) *esize = okd ? 4 : (okh ? 2 : 1);
  }
}

// ---------- fused convert-or-copy -> bf16 for Q,K,WQw,WKw,bq,bk ----------
__global__ void k_prep(const void* __restrict__ Q, unsigned short* __restrict__ Qb,
                       const void* __restrict__ K, unsigned short* __restrict__ Kb,
                       const void* __restrict__ Wq, unsigned short* __restrict__ Wqb,
                       const void* __restrict__ Wk, unsigned short* __restrict__ Wkb,
                       const void* __restrict__ bq, unsigned short* __restrict__ bqb,
                       const void* __restrict__ bk, unsigned short* __restrict__ bkb,
                       const int* __restrict__ bf16flag) {
  int blk = blockIdx.x;
  const void* src; unsigned short* dst; int base, n;
  if (blk < 2048)      { src = Q;  dst = Qb;  base = blk;        n = 8192 * 512; }
  else if (blk < 4096) { src = K;  dst = Kb;  base = blk - 2048; n = 8192 * 512; }
  else if (blk < 4224) { src = Wq; dst = Wqb; base = blk - 4096; n = 512 * 512; }
  else if (blk < 4352) { src = Wk; dst = Wkb; base = blk - 4224; n = 512 * 512; }
  else if (blk == 4352){ src = bq; dst = bqb; base = 0;          n = 512; }
  else                 { src = bk; dst = bkb; base = 0;          n = 512; }
  int i = (base * 256 + threadIdx.x) * 8;
  if (i >= n) return;
  if (*bf16flag) {
    *(uint4*)(dst + i) = *(const uint4*)((const unsigned short*)src + i);
  } else {
    const float* f = (const float*)src + i;
    float4 a = *(const float4*)f, b = *(const float4*)(f + 4);
    uint4 o;
    o.x = (unsigned)f2bf(a.x) | ((unsigned)f2bf(a.y) << 16);
    o.y = (unsigned)f2bf(a.z) | ((unsigned)f2bf(a.w) << 16);
    o.z = (unsigned)f2bf(b.x) | ((unsigned)f2bf(b.y) << 16);
    o.w = (unsigned)f2bf(b.z) | ((unsigned)f2bf(b.w) << 16);
    *(uint4*)(dst + i) = o;
  }
}

// ---------- V [8192x512] -> tiled V^T: Vt[t][d][c], t=vrow/64, c=vrow%64 ----------
// Each 64-k tile is a contiguous 64KB block (kills the 16KB-stride L2 set conflicts).
__global__ void k_transpose_v(const void* __restrict__ Vsrc, const int* __restrict__ bf16flag,
                              unsigned short* __restrict__ Vt) {
  __shared__ unsigned short T[64][72];
  int t = threadIdx.x;
  int rb = blockIdx.x, cb = blockIdx.y;  // rb: V-row tile (64), cb: V-col tile (64)
  int r = t >> 3, c8 = (t & 7) * 8;
  int isbf = *bf16flag;
#pragma unroll
  for (int j = 0; j < 2; j++) {
    int row = rb * 64 + j * 32 + r;
    unsigned short e[8];
    if (isbf) {
      alignas(16) unsigned short tmp[8];
      *(uint4*)tmp = *(const uint4*)((const unsigned short*)Vsrc + (size_t)row * 512 + cb * 64 + c8);
#pragma unroll
      for (int i = 0; i < 8; i++) e[i] = tmp[i];
    } else {
      const float* f = (const float*)Vsrc + (size_t)row * 512 + cb * 64 + c8;
      float4 a = *(const float4*)f, b = *(const float4*)(f + 4);
      e[0] = f2bf(a.x); e[1] = f2bf(a.y); e[2] = f2bf(a.z); e[3] = f2bf(a.w);
      e[4] = f2bf(b.x); e[5] = f2bf(b.y); e[6] = f2bf(b.z); e[7] = f2bf(b.w);
    }
#pragma unroll
    for (int i = 0; i < 8; i++) T[c8 + i][j * 32 + r] = e[i];
  }
  __syncthreads();
#pragma unroll
  for (int j = 0; j < 2; j++) {
    int d = cb * 64 + j * 32 + r;                   // V col = V^T row
    alignas(16) unsigned short o[8];
#pragma unroll
    for (int i = 0; i < 8; i++) o[i] = T[j * 32 + r][c8 + i];
    // tile rb, row d, local cols c8..c8+7
    *(uint4*)(Vt + ((size_t)rb * 512 + d) * 64 + c8) = *(const uint4*)o;
  }
}

// ---------- mask -> bit-packed TRANSPOSED [128 colblk][8192 row] uint64 ----------
DEVFN unsigned nib4(unsigned v) {
  unsigned t = v; t |= t >> 1; t |= t >> 2; t |= t >> 4; t &= 0x01010101u;
  return (t * 0x10204080u) >> 28;
}
DEVFN unsigned pair2(unsigned v) {
  unsigned t = v; t |= t >> 8; t |= t >> 4; t |= t >> 2; t |= t >> 1;
  return (t & 1u) | (((t >> 16) & 1u) << 1);
}
__global__ void k_pack(const void* __restrict__ mask, const int* __restrict__ esize,
                       unsigned long long* __restrict__ bits) {
  int wv = (blockIdx.x * blockDim.x + threadIdx.x) >> 6;  // 4096 waves
  int lane = threadIdx.x & 63;
  int sz = *esize;
  const uint4* m = (const uint4*)mask;
  if (sz == 4) {
    for (int g = wv; g < 262144; g += 4096) {
      uint4 v = m[(size_t)g * 64 + lane];
      unsigned nib = (v.x != 0u) | ((v.y != 0u) << 1) | ((v.z != 0u) << 2) | ((v.w != 0u) << 3);
      unsigned long long x = (unsigned long long)nib << ((lane & 15) * 4);
      x |= __shfl_xor(x, 1); x |= __shfl_xor(x, 2);
      x |= __shfl_xor(x, 4); x |= __shfl_xor(x, 8);
      if ((lane & 15) == 0) {
        int w = g * 4 + (lane >> 4);
        bits[(size_t)(w & 127) * 8192 + (w >> 7)] = x;
      }
    }
  } else if (sz == 2) {
    for (int g = wv; g < 32768; g += 4096) {
      uint4 v = m[(size_t)g * 64 + lane];
      unsigned c8 = pair2(v.x) | (pair2(v.y) << 2) | (pair2(v.z) << 4) | (pair2(v.w) << 6);
      unsigned long long x = (unsigned long long)c8 << ((lane & 7) * 8);
      x |= __shfl_xor(x, 1); x |= __shfl_xor(x, 2); x |= __shfl_xor(x, 4);
      if ((lane & 7) == 0) {
        int w = g * 8 + (lane >> 3);
        bits[(size_t)(w & 127) * 8192 + (w >> 7)] = x;
      }
    }
  } else {
    for (int g = wv; g < 16384; g += 4096) {
      uint4 v = m[(size_t)g * 64 + lane];
      unsigned c16 = nib4(v.x) | (nib4(v.y) << 4) | (nib4(v.z) << 8) | (nib4(v.w) << 12);
      unsigned long long x = (unsigned long long)c16 << ((lane & 3) * 16);
      x |= __shfl_xor(x, 1); x |= __shfl_xor(x, 2);
      if ((lane & 3) == 0) {
        int w = g * 16 + (lane >> 2);
        bits[(size_t)(w & 127) * 8192 + (w >> 7)] = x;
      }
    }
  }
}

// ---------- fused proj GEMM (z=0: Q, z=1: K): out = A @ W^T + bias, bf16 ----------
__global__ __launch_bounds__(256, 2) void k_proj(
    const unsigned short* __restrict__ Aq, const unsigned short* __restrict__ Wq,
    const unsigned short* __restrict__ bq, unsigned short* __restrict__ outq,
    const unsigned short* __restrict__ Ak, const unsigned short* __restrict__ Wk,
    const unsigned short* __restrict__ bk, unsigned short* __restrict__ outk) {
  const unsigned short* A = blockIdx.z ? Ak : Aq;
  const unsigned short* W = blockIdx.z ? Wk : Wq;
  const unsigned short* bias = blockIdx.z ? bk : bq;
  unsigned short* out = blockIdx.z ? outk : outq;

  __shared__ alignas(16) unsigned short As[128 * 64];
  __shared__ alignas(16) unsigned short Bs[128 * 64];
  int tid = threadIdx.x, lane = tid & 63, wave = tid >> 6;
  int wi = wave >> 1, wj = wave & 1;
  int l15 = lane & 15, l4 = lane >> 4;
  int rowbase = blockIdx.x * 128, colbase = blockIdx.y * 128;
  f32x4 acc[4][4];
#pragma unroll
  for (int i = 0; i < 4; i++)
#pragma unroll
    for (int j = 0; j < 4; j++) acc[i][j] = f32x4{0.f, 0.f, 0.f, 0.f};

  int swr = l15 & 7;
  for (int kb = 0; kb < 512; kb += 64) {
    __syncthreads();
#pragma unroll
    for (int t = 0; t < 4; t++) {
      int inst = wave * 4 + t;
      int r = inst * 8 + (lane >> 3);
      int c = ((lane & 7) ^ (r & 7)) * 8;
      gl_lds16(A + (size_t)(rowbase + r) * 512 + kb + c, &As[inst * 512]);
      gl_lds16(W + (size_t)(colbase + r) * 512 + kb + c, &Bs[inst * 512]);
    }
    __syncthreads();
#pragma unroll
    for (int t2 = 0; t2 < 2; t2++) {
      short8 a[4], b[4];
#pragma unroll
      for (int i = 0; i < 4; i++) {
        int row = wi * 64 + i * 16 + l15;
        a[i] = *(const short8*)&As[row * 64 + (((t2 * 4 + l4) ^ swr) * 8)];
      }
#pragma unroll
      for (int j = 0; j < 4; j++) {
        int row = wj * 64 + j * 16 + l15;
        b[j] = *(const short8*)&Bs[row * 64 + (((t2 * 4 + l4) ^ swr) * 8)];
      }
#pragma unroll
      for (int i = 0; i < 4; i++)
#pragma unroll
        for (int j = 0; j < 4; j++)
          acc[i][j] = __builtin_amdgcn_mfma_f32_16x16x32_bf16(a[i], b[j], acc[i][j], 0, 0, 0);
    }
  }
#pragma unroll
  for (int j = 0; j < 4; j++) {
    int col = colbase + wj * 64 + j * 16 + l15;
    float bj = bf2f(bias[col]);
#pragma unroll
    for (int i = 0; i < 4; i++) {
      int row0 = rowbase + wi * 64 + i * 16 + l4 * 4;
#pragma unroll
      for (int r = 0; r < 4; r++)
        out[(size_t)(row0 + r) * 512 + col] = f2bf(acc[i][j][r] + bj);
    }
  }
}

// ---------- flash attention: BM=64 (4 waves), BN=64, split-K=8 ----------
// V^T is tile-contiguous (64KB blocks) -> L2-friendly. Opart f-major coalesced bf16.
__global__ __launch_bounds__(256, 2) void k_attn(
    const unsigned short* __restrict__ Qp, const unsigned short* __restrict__ Kp,
    const unsigned short* __restrict__ Vt, const unsigned long long* __restrict__ mbits,
    unsigned short* __restrict__ Opart, float* __restrict__ mpart, float* __restrict__ lpart) {
  __shared__ alignas(16) unsigned short SH[32768];  // 64KB: K-tile 64x512 | V^T-tile 512x64
  __shared__ alignas(16) unsigned short P[64 * 64]; // 8KB
  int tid = threadIdx.x, lane = tid & 63, wave = tid >> 6;
  int l15 = lane & 15, l4 = lane >> 4;
  int b = blockIdx.x;
  int split = b & 7;
  int qb = (b >> 3) * 64;

  short8 qf[16];  // persistent Q fragments
  {
    int row = qb + wave * 16 + l15;
#pragma unroll
    for (int t = 0; t < 16; t++)
      qf[t] = *(const short8*)(Qp + (size_t)row * 512 + t * 32 + l4 * 8);
  }
  f32x4 o[32];
#pragma unroll
  for (int f = 0; f < 32; f++) o[f] = f32x4{0.f, 0.f, 0.f, 0.f};
  float mi[4] = {NEGF, NEGF, NEGF, NEGF};
  float li[4] = {0.f, 0.f, 0.f, 0.f};

  int swK = l15 | ((l15 & 3) << 4);
  int swP_rd = (l15 & 7) ^ ((l15 & 8) >> 2);

  for (int it = 0; it < 16; it++) {
    int tglob = split * 16 + it;
    int kb = tglob * 64;
    unsigned long long mw[4];
#pragma unroll
    for (int r = 0; r < 4; r++)
      mw[r] = mbits[(size_t)tglob * 8192 + (qb + wave * 16 + l4 * 4 + r)];

    __syncthreads();  // A: SH safe to overwrite
#pragma unroll
    for (int t = 0; t < 16; t++) {
      int inst = wave * 16 + t;  // K row 0..63
      int swz = (inst & 15) | ((inst & 3) << 4);
      gl_lds16(Kp + (size_t)(kb + inst) * 512 + ((lane ^ swz) * 8), &SH[inst * 512]);
    }
    __syncthreads();  // B: K staged

    f32x4 sacc[4];
#pragma unroll
    for (int c = 0; c < 4; c++) sacc[c] = f32x4{0.f, 0.f, 0.f, 0.f};
#pragma unroll
    for (int t2 = 0; t2 < 16; t2++) {
      short8 a = qf[t2];
#pragma unroll
      for (int c = 0; c < 4; c++) {
        int row = c * 16 + l15;
        short8 bb = *(const short8*)&SH[row * 512 + (((t2 * 4 + l4) ^ swK) * 8)];
        sacc[c] = __builtin_amdgcn_mfma_f32_16x16x32_bf16(a, bb, sacc[c], 0, 0, 0);
      }
    }

#pragma unroll
    for (int c = 0; c < 4; c++)
#pragma unroll
      for (int r = 0; r < 4; r++) {
        float s = sacc[c][r] * SCALE_ATTN;
        bool msk = (mw[r] >> (c * 16 + l15)) & 1ULL;
        sacc[c][r] = msk ? NEGF : s;
      }

    float alpha[4], mnew[4];
#pragma unroll
    for (int r = 0; r < 4; r++) {
      float t = fmaxf(fmaxf(sacc[0][r], sacc[1][r]), fmaxf(sacc[2][r], sacc[3][r]));
#pragma unroll
      for (int off = 1; off < 16; off <<= 1) t = fmaxf(t, __shfl_xor(t, off, 64));
      float mn = fmaxf(mi[r], t);
      alpha[r] = __expf(mi[r] - mn);
      mi[r] = mn; mnew[r] = mn;
    }
#pragma unroll
    for (int c = 0; c < 4; c++)
#pragma unroll
      for (int r = 0; r < 4; r++)
        sacc[c][r] = __expf(sacc[c][r] - mnew[r]);
#pragma unroll
    for (int r = 0; r < 4; r++) {
      float t = sacc[0][r] + sacc[1][r] + sacc[2][r] + sacc[3][r];
#pragma unroll
      for (int off = 1; off < 16; off <<= 1) t += __shfl_xor(t, off, 64);
      li[r] = li[r] * alpha[r] + t;
    }

#pragma unroll
    for (int r = 0; r < 4; r++) {
      int prow = wave * 16 + l4 * 4 + r;
      int s = (prow & 7) ^ ((prow & 8) >> 2);
#pragma unroll
      for (int c = 0; c < 4; c++) {
        int chunk = (c * 2 + (l15 >> 3)) ^ s;
        P[prow * 64 + chunk * 8 + (l15 & 7)] = f2bf(sacc[c][r]);
      }
    }
#pragma unroll
    for (int f = 0; f < 32; f++)
#pragma unroll
      for (int r = 0; r < 4; r++) o[f][r] *= alpha[r];

    __syncthreads();  // C: P visible, K reads done
    // stage tiled V^T: contiguous 64KB block at tglob*32768 shorts
#pragma unroll
    for (int t = 0; t < 16; t++) {
      int inst = wave * 16 + t;
      int d = inst * 8 + (lane >> 3);
      int cc = lane & 7;
      gl_lds16(Vt + (size_t)tglob * 32768 + d * 64 + ((cc ^ (d & 7)) * 8), &SH[inst * 512]);
    }
    __syncthreads();  // D: V staged

#pragma unroll
    for (int u = 0; u < 2; u++) {
      int prow = wave * 16 + l15;
      short8 a = *(const short8*)&P[prow * 64 + (((u * 4 + l4) ^ swP_rd) * 8)];
#pragma unroll
      for (int f = 0; f < 32; f++) {
        int vrow = f * 16 + l15;
        short8 bb = *(const short8*)&SH[vrow * 64 + (((u * 4 + l4) ^ (l15 & 7)) * 8)];
        o[f] = __builtin_amdgcn_mfma_f32_16x16x32_bf16(a, bb, o[f], 0, 0, 0);
      }
    }
  }

  // ---- epilogue: m/l + f-major coalesced bf16 partials ----
#pragma unroll
  for (int r = 0; r < 4; r++) {
    int row = qb + wave * 16 + l4 * 4 + r;
    if (l15 == 0) {
      mpart[(size_t)split * 8192 + row] = mi[r];
      lpart[(size_t)split * 8192 + row] = li[r];
    }
  }
  uint2* op = (uint2*)Opart;
#pragma unroll
  for (int f = 0; f < 32; f++) {
    uint2 v;
    v.x = (unsigned)f2bf(o[f][0]) | ((unsigned)f2bf(o[f][1]) << 16);
    v.y = (unsigned)f2bf(o[f][2]) | ((unsigned)f2bf(o[f][3]) << 16);
    op[((size_t)b * 32 + f) * 256 + tid] = v;
  }
}

// ---------- combine 8 split-K partials (f-major bf16) -> f32 out ----------
__global__ void k_combine(const unsigned short* __restrict__ Opart,
                          const float* __restrict__ mpart, const float* __restrict__ lpart,
                          float* __restrict__ out) {
  int q = blockIdx.x;                 // 0..127 (qb tile)
  int half = blockIdx.y;              // 0..1
  int tid = threadIdx.x;
  int wave = tid >> 6, l4 = (tid >> 4) & 3, l15 = tid & 15;
  int row0 = q * 64 + wave * 16 + l4 * 4;

  float w[8][4], inv[4];
#pragma unroll
  for (int r = 0; r < 4; r++) {
    float M = NEGF;
    float mv[8];
#pragma unroll
    for (int s = 0; s < 8; s++) { mv[s] = mpart[s * 8192 + row0 + r]; M = fmaxf(M, mv[s]); }
    float L = 0.f;
#pragma unroll
    for (int s = 0; s < 8; s++) {
      float ws = __expf(mv[s] - M);
      w[s][r] = ws;
      L += ws * lpart[s * 8192 + row0 + r];
    }
    inv[r] = 1.0f / L;
  }
  const uint2* op = (const uint2*)Opart;
#pragma unroll
  for (int fo = 0; fo < 16; fo++) {
    int f = half * 16 + fo;
    float acc[4] = {0.f, 0.f, 0.f, 0.f};
#pragma unroll
    for (int s = 0; s < 8; s++) {
      uint2 v = op[((size_t)(q * 8 + s) * 32 + f) * 256 + tid];
      acc[0] += w[s][0] * bf2f((unsigned short)(v.x & 0xFFFFu));
      acc[1] += w[s][1] * bf2f((unsigned short)(v.x >> 16));
      acc[2] += w[s][2] * bf2f((unsigned short)(v.y & 0xFFFFu));
      acc[3] += w[s][3] * bf2f((unsigned short)(v.y >> 16));
    }
    int col = f * 16 + l15;
#pragma unroll
    for (int r = 0; r < 4; r++)
      out[(size_t)(row0 + r) * 512 + col] = acc[r] * inv[r];
  }
}

extern "C" void kernel_launch(void* const* d_in, const int* in_sizes, int n_in,
                              void* d_out, int out_size, void* d_ws, size_t ws_size,
                              hipStream_t stream) {
  const void* Q   = d_in[0];
  const void* K   = d_in[1];
  const void* V   = d_in[2];
  const void* WQw = d_in[3];
  const void* WQb = d_in[4];
  const void* WKw = d_in[5];
  const void* WKb = d_in[6];
  const void* mask = d_in[7];
  float* out = (float*)d_out;
  char* ws = (char*)d_ws;
  (void)in_sizes; (void)n_in; (void)out_size; (void)ws_size;

  constexpr size_t SZ_MAT = (size_t)8192 * 512 * 2;  // 8 MB bf16
  size_t off = 4096;
  unsigned short* Qb  = (unsigned short*)(ws + off); off += SZ_MAT;
  unsigned short* Kb  = (unsigned short*)(ws + off); off += SZ_MAT;
  unsigned short* Wqb = (unsigned short*)(ws + off); off += (size_t)512 * 512 * 2;
  unsigned short* Wkb = (unsigned short*)(ws + off); off += (size_t)512 * 512 * 2;
  unsigned short* bqb = (unsigned short*)(ws + off); off += 1024;
  unsigned short* bkb = (unsigned short*)(ws + off); off += 1024;
  unsigned short* Vt  = (unsigned short*)(ws + off); off += SZ_MAT;
  unsigned short* Qp  = (unsigned short*)(ws + off); off += SZ_MAT;
  unsigned short* Kp  = (unsigned short*)(ws + off); off += SZ_MAT;
  unsigned long long* mbits = (unsigned long long*)(ws + off); off += (size_t)8192 * 128 * 8;
  unsigned short* Opart = (unsigned short*)(ws + off); off += (size_t)1024 * 256 * 32 * 8;  // 64 MB
  float* mpart = (float*)(ws + off); off += (size_t)8 * 8192 * 4;
  float* lpart = (float*)(ws + off); off += (size_t)8 * 8192 * 4;
  int* fflag = (int*)ws;
  int* esize = (int*)(ws + 64);

  k_detect<<<2, 64, 0, stream>>>((const unsigned int*)Q, (const unsigned int*)mask, fflag, esize);
  k_prep<<<4354, 256, 0, stream>>>(Q, Qb, K, Kb, WQw, Wqb, WKw, Wkb, WQb, bqb, WKb, bkb, fflag);
  k_transpose_v<<<dim3(128, 8), 256, 0, stream>>>(V, fflag, Vt);
  k_pack<<<1024, 256, 0, stream>>>(mask, esize, mbits);
  k_proj<<<dim3(64, 4, 2), 256, 0, stream>>>(Qb, Wqb, bqb, Qp, Kb, Wkb, bkb, Kp);
  k_attn<<<1024, 256, 0, stream>>>(Qp, Kp, Vt, mbits, Opart, mpart, lpart);
  k_combine<<<dim3(128, 2), 256, 0, stream>>>(Opart, mpart, lpart, out);
}

// Round 8
// 823.242 us; speedup vs baseline: 1.8143x; 1.6367x over previous
//
#include <hip/hip_runtime.h>

typedef __attribute__((ext_vector_type(8))) short short8;
typedef __attribute__((ext_vector_type(4))) float f32x4;

#define DEVFN __device__ __forceinline__

constexpr float SCALE_ATTN = 0.04419417382415922f;  // 1/sqrt(512)
constexpr float NEGF = -4294967296.0f;              // -(1<<32)

DEVFN unsigned short f2bf(float f) {
  unsigned int u = __float_as_uint(f);
  u += 0x7FFFu + ((u >> 16) & 1u);   // RNE (inputs finite)
  return (unsigned short)(u >> 16);
}
DEVFN float bf2f(unsigned short h) { return __uint_as_float((unsigned)h << 16); }

DEVFN void gl_lds16(const void* g, void* l) {
  __builtin_amdgcn_global_load_lds(
      (const __attribute__((address_space(1))) unsigned int*)g,
      (__attribute__((address_space(3))) unsigned int*)l, 16, 0, 0);
}

// ---------- merged detectors: block 0 = Q dtype, block 1 = mask esize ----------
__global__ void k_detect(const unsigned int* __restrict__ q, const unsigned int* __restrict__ m,
                         int* __restrict__ fflag, int* __restrict__ esize) {
  int lane = threadIdx.x;
  if (blockIdx.x == 0) {
    unsigned bad = 0;
    for (int i = 0; i < 64; i++) {
      unsigned v = q[i * 64 + lane];
      unsigned h = v & 0xFFFFu;
      unsigned e = (h >> 7) & 0xFFu;
      if (h != 0u && (e < 96u || e > 150u)) bad = 1;
    }
    unsigned long long anyb = __ballot(bad != 0);
    if (lane == 0) *fflag = (anyb == 0ULL) ? 1 : 0;
  } else {
    unsigned okd = 1, okh = 1, okb = 1;
    for (int i = 0; i < 64; i++) {
      unsigned v = m[i * 64 + lane];
      if (v > 1u && v != 0x3F800000u) okd = 0;   // int32/f32 0|1|1.0f
      unsigned h0 = v & 0xFFFFu, h1 = v >> 16;
      if ((h0 && h0 != 0x3F80u && h0 != 1u) || (h1 && h1 != 0x3F80u && h1 != 1u)) okh = 0;
      if (v & 0xFEFEFEFEu) okb = 0;
    }
    okd = (__ballot(okd == 0) == 0ULL);
    okh = (__ballot(okh == 0) == 0ULL);
    okb = (__ballot(okb == 0) == 0ULL);
    if (lane == 0) *esize = okd ? 4 : (okh ? 2 : 1);
  }
}

// ---------- fused convert-or-copy -> bf16 for Q,K,WQw,WKw,bq,bk ----------
__global__ void k_prep(const void* __restrict__ Q, unsigned short* __restrict__ Qb,
                       const void* __restrict__ K, unsigned short* __restrict__ Kb,
                       const void* __restrict__ Wq, unsigned short* __restrict__ Wqb,
                       const void* __restrict__ Wk, unsigned short* __restrict__ Wkb,
                       const void* __restrict__ bq, unsigned short* __restrict__ bqb,
                       const void* __restrict__ bk, unsigned short* __restrict__ bkb,
                       const int* __restrict__ bf16flag) {
  int blk = blockIdx.x;
  const void* src; unsigned short* dst; int base, n;
  if (blk < 2048)      { src = Q;  dst = Qb;  base = blk;        n = 8192 * 512; }
  else if (blk < 4096) { src = K;  dst = Kb;  base = blk - 2048; n = 8192 * 512; }
  else if (blk < 4224) { src = Wq; dst = Wqb; base = blk - 4096; n = 512 * 512; }
  else if (blk < 4352) { src = Wk; dst = Wkb; base = blk - 4224; n = 512 * 512; }
  else if (blk == 4352){ src = bq; dst = bqb; base = 0;          n = 512; }
  else                 { src = bk; dst = bkb; base = 0;          n = 512; }
  int i = (base * 256 + threadIdx.x) * 8;
  if (i >= n) return;
  if (*bf16flag) {
    *(uint4*)(dst + i) = *(const uint4*)((const unsigned short*)src + i);
  } else {
    const float* f = (const float*)src + i;
    float4 a = *(const float4*)f, b = *(const float4*)(f + 4);
    uint4 o;
    o.x = (unsigned)f2bf(a.x) | ((unsigned)f2bf(a.y) << 16);
    o.y = (unsigned)f2bf(a.z) | ((unsigned)f2bf(a.w) << 16);
    o.z = (unsigned)f2bf(b.x) | ((unsigned)f2bf(b.y) << 16);
    o.w = (unsigned)f2bf(b.z) | ((unsigned)f2bf(b.w) << 16);
    *(uint4*)(dst + i) = o;
  }
}

// ---------- V [8192x512] -> tiled V^T: Vt[t][d][c], tiles of 32 k-rows ----------
__global__ void k_transpose_v(const void* __restrict__ Vsrc, const int* __restrict__ bf16flag,
                              unsigned short* __restrict__ Vt) {
  __shared__ unsigned short T[64][72];
  int t = threadIdx.x;
  int rb = blockIdx.x, cb = blockIdx.y;
  int r = t >> 3, c8 = (t & 7) * 8;
  int isbf = *bf16flag;
#pragma unroll
  for (int j = 0; j < 2; j++) {
    int row = rb * 64 + j * 32 + r;
    unsigned short e[8];
    if (isbf) {
      alignas(16) unsigned short tmp[8];
      *(uint4*)tmp = *(const uint4*)((const unsigned short*)Vsrc + (size_t)row * 512 + cb * 64 + c8);
#pragma unroll
      for (int i = 0; i < 8; i++) e[i] = tmp[i];
    } else {
      const float* f = (const float*)Vsrc + (size_t)row * 512 + cb * 64 + c8;
      float4 a = *(const float4*)f, b = *(const float4*)(f + 4);
      e[0] = f2bf(a.x); e[1] = f2bf(a.y); e[2] = f2bf(a.z); e[3] = f2bf(a.w);
      e[4] = f2bf(b.x); e[5] = f2bf(b.y); e[6] = f2bf(b.z); e[7] = f2bf(b.w);
    }
#pragma unroll
    for (int i = 0; i < 8; i++) T[c8 + i][j * 32 + r] = e[i];
  }
  __syncthreads();
#pragma unroll
  for (int j = 0; j < 2; j++) {
    int d = cb * 64 + j * 32 + r;                   // V col = V^T row
    alignas(16) unsigned short o[8];
#pragma unroll
    for (int i = 0; i < 8; i++) o[i] = T[j * 32 + r][c8 + i];
    int tt = rb * 2 + (c8 >> 5);
    *(uint4*)(Vt + ((size_t)tt * 512 + d) * 32 + (c8 & 31)) = *(const uint4*)o;
  }
}

// ---------- mask -> bit-packed row-major [8192][128] uint64 ----------
DEVFN unsigned nib4(unsigned v) {
  unsigned t = v; t |= t >> 1; t |= t >> 2; t |= t >> 4; t &= 0x01010101u;
  return (t * 0x10204080u) >> 28;
}
DEVFN unsigned pair2(unsigned v) {
  unsigned t = v; t |= t >> 8; t |= t >> 4; t |= t >> 2; t |= t >> 1;
  return (t & 1u) | (((t >> 16) & 1u) << 1);
}
__global__ void k_pack(const void* __restrict__ mask, const int* __restrict__ esize,
                       unsigned long long* __restrict__ bits) {
  int wv = (blockIdx.x * blockDim.x + threadIdx.x) >> 6;  // 4096 waves
  int lane = threadIdx.x & 63;
  int sz = *esize;
  if (sz == 4) {
    const unsigned int* m = (const unsigned int*)mask;
    for (int g = wv; g < 262144; g += 4096) {
      size_t base = (size_t)g * 256 + lane;
      unsigned v0 = m[base], v1 = m[base + 64], v2 = m[base + 128], v3 = m[base + 192];
      unsigned long long b0 = __ballot(v0 != 0u);
      unsigned long long b1 = __ballot(v1 != 0u);
      unsigned long long b2 = __ballot(v2 != 0u);
      unsigned long long b3 = __ballot(v3 != 0u);
      if (lane == 0) {
        bits[g * 4 + 0] = b0; bits[g * 4 + 1] = b1;
        bits[g * 4 + 2] = b2; bits[g * 4 + 3] = b3;
      }
    }
  } else if (sz == 2) {
    const uint4* m = (const uint4*)mask;
    for (int g = wv; g < 131072; g += 4096) {
      uint4 v = m[(size_t)g * 64 + lane];
      unsigned c8 = pair2(v.x) | (pair2(v.y) << 2) | (pair2(v.z) << 4) | (pair2(v.w) << 6);
      unsigned long long x = (unsigned long long)c8 << ((lane & 7) * 8);
      x |= __shfl_xor(x, 1); x |= __shfl_xor(x, 2); x |= __shfl_xor(x, 4);
      if ((lane & 7) == 0) bits[g * 8 + (lane >> 3)] = x;
    }
  } else {
    const uint4* m = (const uint4*)mask;
    for (int g = wv; g < 65536; g += 4096) {
      uint4 v = m[(size_t)g * 64 + lane];
      unsigned c16 = nib4(v.x) | (nib4(v.y) << 4) | (nib4(v.z) << 8) | (nib4(v.w) << 12);
      unsigned long long x = (unsigned long long)c16 << ((lane & 3) * 16);
      x |= __shfl_xor(x, 1); x |= __shfl_xor(x, 2);
      if ((lane & 3) == 0) bits[g * 16 + (lane >> 2)] = x;
    }
  }
}

// ---------- fused proj GEMM (z=0: Q, z=1: K): out = A @ W^T + bias, bf16 ----------
__global__ __launch_bounds__(256, 2) void k_proj(
    const unsigned short* __restrict__ Aq, const unsigned short* __restrict__ Wq,
    const unsigned short* __restrict__ bq, unsigned short* __restrict__ outq,
    const unsigned short* __restrict__ Ak, const unsigned short* __restrict__ Wk,
    const unsigned short* __restrict__ bk, unsigned short* __restrict__ outk) {
  const unsigned short* A = blockIdx.z ? Ak : Aq;
  const unsigned short* W = blockIdx.z ? Wk : Wq;
  const unsigned short* bias = blockIdx.z ? bk : bq;
  unsigned short* out = blockIdx.z ? outk : outq;

  __shared__ alignas(16) unsigned short As[128 * 64];
  __shared__ alignas(16) unsigned short Bs[128 * 64];
  int tid = threadIdx.x, lane = tid & 63, wave = tid >> 6;
  int wi = wave >> 1, wj = wave & 1;
  int l15 = lane & 15, l4 = lane >> 4;
  int rowbase = blockIdx.x * 128, colbase = blockIdx.y * 128;
  f32x4 acc[4][4];
#pragma unroll
  for (int i = 0; i < 4; i++)
#pragma unroll
    for (int j = 0; j < 4; j++) acc[i][j] = f32x4{0.f, 0.f, 0.f, 0.f};

  int swr = l15 & 7;
  for (int kb = 0; kb < 512; kb += 64) {
    __syncthreads();
#pragma unroll
    for (int t = 0; t < 4; t++) {
      int inst = wave * 4 + t;
      int r = inst * 8 + (lane >> 3);
      int c = ((lane & 7) ^ (r & 7)) * 8;
      gl_lds16(A + (size_t)(rowbase + r) * 512 + kb + c, &As[inst * 512]);
      gl_lds16(W + (size_t)(colbase + r) * 512 + kb + c, &Bs[inst * 512]);
    }
    __syncthreads();
#pragma unroll
    for (int t2 = 0; t2 < 2; t2++) {
      short8 a[4], b[4];
#pragma unroll
      for (int i = 0; i < 4; i++) {
        int row = wi * 64 + i * 16 + l15;
        a[i] = *(const short8*)&As[row * 64 + (((t2 * 4 + l4) ^ swr) * 8)];
      }
#pragma unroll
      for (int j = 0; j < 4; j++) {
        int row = wj * 64 + j * 16 + l15;
        b[j] = *(const short8*)&Bs[row * 64 + (((t2 * 4 + l4) ^ swr) * 8)];
      }
#pragma unroll
      for (int i = 0; i < 4; i++)
#pragma unroll
        for (int j = 0; j < 4; j++)
          acc[i][j] = __builtin_amdgcn_mfma_f32_16x16x32_bf16(a[i], b[j], acc[i][j], 0, 0, 0);
    }
  }
#pragma unroll
  for (int j = 0; j < 4; j++) {
    int col = colbase + wj * 64 + j * 16 + l15;
    float bj = bf2f(bias[col]);
#pragma unroll
    for (int i = 0; i < 4; i++) {
      int row0 = rowbase + wi * 64 + i * 16 + l4 * 4;
#pragma unroll
      for (int r = 0; r < 4; r++)
        out[(size_t)(row0 + r) * 512 + col] = f2bf(acc[i][j][r] + bj);
    }
  }
}

// ---------- flash attention: BM=128 (8 waves), BN=32, split-K=8, 2-barrier pipeline ----------
// LDS: Kbuf 32KB + Vbuf 32KB + P 8KB = 72KB. 512 blocks (1/CU, 8 waves/CU reg-capped).
// Pipeline: [barrier A: K(it) landed, Vbuf free] issue V(it); QK^T+softmax (hides V)
//           [barrier B: V(it) landed, P visible, Kbuf free] issue K(it+1); PV (hides K).
__global__ __launch_bounds__(512, 2) void k_attn(
    const unsigned short* __restrict__ Qp, const unsigned short* __restrict__ Kp,
    const unsigned short* __restrict__ Vt, const unsigned long long* __restrict__ mbits,
    unsigned short* __restrict__ Opart, float* __restrict__ mpart, float* __restrict__ lpart) {
  __shared__ alignas(16) unsigned short KB[16384];  // 32 rows x 512
  __shared__ alignas(16) unsigned short VB[16384];  // 512 d-rows x 32
  __shared__ alignas(16) unsigned short P[128 * 32];
  int tid = threadIdx.x, lane = tid & 63, wave = tid >> 6;
  int l15 = lane & 15, l4 = lane >> 4;
  int b = blockIdx.x;
  int split = b & 7;
  int qb = (b >> 3) * 128;

  short8 qf[16];  // persistent Q fragments: wave's 16 rows x 512
  {
    int row = qb + wave * 16 + l15;
#pragma unroll
    for (int t = 0; t < 16; t++)
      qf[t] = *(const short8*)(Qp + (size_t)row * 512 + t * 32 + l4 * 8);
  }
  f32x4 o[32];
#pragma unroll
  for (int f = 0; f < 32; f++) o[f] = f32x4{0.f, 0.f, 0.f, 0.f};
  float mi[4] = {NEGF, NEGF, NEGF, NEGF};
  float li[4] = {0.f, 0.f, 0.f, 0.f};

  int swK = l15 | ((l15 & 3) << 4);   // K read swizzle (matches deposit swz(row))

  // prologue: stage K(0)
  {
    int tv = split * 32;
#pragma unroll
    for (int t = 0; t < 4; t++) {
      int r = wave * 4 + t;  // 32 rows / 8 waves
      int swz = (r & 15) | ((r & 3) << 4);
      gl_lds16(Kp + (size_t)(tv * 32 + r) * 512 + ((lane ^ swz) * 8), &KB[r * 512]);
    }
  }

  for (int it = 0; it < 32; it++) {
    int tv = split * 32 + it;
    unsigned long long mw[4];
#pragma unroll
    for (int r = 0; r < 4; r++)
      mw[r] = mbits[(size_t)(qb + wave * 16 + l4 * 4 + r) * 128 + split * 16 + (it >> 1)];
    int mshift = (it & 1) * 32;

    __syncthreads();  // A: K(it) landed; Vbuf free (PV(it-1) done)

    // issue V(it) -> VB (hidden by QK^T + softmax); each inst = 512 shorts (16 d-rows)
#pragma unroll
    for (int t = 0; t < 4; t++) {
      int inst = wave * 4 + t;             // 32 insts, 16 d-rows each
      int d = inst * 16 + (lane >> 2);
      int cg = (lane & 3) ^ (d & 3);
      gl_lds16(Vt + (size_t)tv * 16384 + d * 32 + cg * 8, &VB[inst * 512]);
    }

    // ---- S = Q K^T (128x32) ----
    f32x4 sacc[2];
#pragma unroll
    for (int c = 0; c < 2; c++) sacc[c] = f32x4{0.f, 0.f, 0.f, 0.f};
#pragma unroll
    for (int t2 = 0; t2 < 16; t2++) {
      short8 a = qf[t2];
#pragma unroll
      for (int c = 0; c < 2; c++) {
        int row = c * 16 + l15;
        short8 bb = *(const short8*)&KB[row * 512 + (((t2 * 4 + l4) ^ swK) * 8)];
        sacc[c] = __builtin_amdgcn_mfma_f32_16x16x32_bf16(a, bb, sacc[c], 0, 0, 0);
      }
    }

    // ---- scale + mask ----
#pragma unroll
    for (int c = 0; c < 2; c++)
#pragma unroll
      for (int r = 0; r < 4; r++) {
        float s = sacc[c][r] * SCALE_ATTN;
        bool msk = (mw[r] >> (mshift + c * 16 + l15)) & 1ULL;
        sacc[c][r] = msk ? NEGF : s;
      }

    // ---- online softmax ----
    float alpha[4], mnew[4];
#pragma unroll
    for (int r = 0; r < 4; r++) {
      float t = fmaxf(sacc[0][r], sacc[1][r]);
#pragma unroll
      for (int off = 1; off < 16; off <<= 1) t = fmaxf(t, __shfl_xor(t, off, 64));
      float mn = fmaxf(mi[r], t);
      alpha[r] = __expf(mi[r] - mn);
      mi[r] = mn; mnew[r] = mn;
    }
#pragma unroll
    for (int c = 0; c < 2; c++)
#pragma unroll
      for (int r = 0; r < 4; r++)
        sacc[c][r] = __expf(sacc[c][r] - mnew[r]);
#pragma unroll
    for (int r = 0; r < 4; r++) {
      float t = sacc[0][r] + sacc[1][r];
#pragma unroll
      for (int off = 1; off < 16; off <<= 1) t += __shfl_xor(t, off, 64);
      li[r] = li[r] * alpha[r] + t;
    }

    // ---- P -> LDS (swizzled: chunk ^ (prow&3)) ----
#pragma unroll
    for (int r = 0; r < 4; r++) {
      int prow = wave * 16 + l4 * 4 + r;
#pragma unroll
      for (int c = 0; c < 2; c++) {
        int chunk = (c * 2 + (l15 >> 3)) ^ (r & 3);
        P[prow * 32 + chunk * 8 + (l15 & 7)] = f2bf(sacc[c][r]);
      }
    }
#pragma unroll
    for (int f = 0; f < 32; f++)
#pragma unroll
      for (int r = 0; r < 4; r++) o[f][r] *= alpha[r];

    __syncthreads();  // B: V(it) landed, P visible, Kbuf free

    // issue K(it+1) -> KB (hidden by PV)
    {
      int tv1 = (it < 31) ? tv + 1 : tv;
#pragma unroll
      for (int t = 0; t < 4; t++) {
        int r = wave * 4 + t;
        int swz = (r & 15) | ((r & 3) << 4);
        gl_lds16(Kp + (size_t)(tv1 * 32 + r) * 512 + ((lane ^ swz) * 8), &KB[r * 512]);
      }
    }

    // ---- O += P @ V (k=32, one MFMA per d-frag) ----
    {
      int prow = wave * 16 + l15;
      short8 a = *(const short8*)&P[prow * 32 + ((l4 ^ (l15 & 3)) * 8)];
#pragma unroll
      for (int f = 0; f < 32; f++) {
        int d = f * 16 + l15;
        short8 bb = *(const short8*)&VB[d * 32 + ((l4 ^ (l15 & 3)) * 8)];
        o[f] = __builtin_amdgcn_mfma_f32_16x16x32_bf16(a, bb, o[f], 0, 0, 0);
      }
    }
  }

  // ---- epilogue: m/l + f-major coalesced bf16 partials ----
#pragma unroll
  for (int r = 0; r < 4; r++) {
    int row = qb + wave * 16 + l4 * 4 + r;
    if (l15 == 0) {
      mpart[(size_t)split * 8192 + row] = mi[r];
      lpart[(size_t)split * 8192 + row] = li[r];
    }
  }
  uint2* op = (uint2*)Opart;
#pragma unroll
  for (int f = 0; f < 32; f++) {
    uint2 v;
    v.x = (unsigned)f2bf(o[f][0]) | ((unsigned)f2bf(o[f][1]) << 16);
    v.y = (unsigned)f2bf(o[f][2]) | ((unsigned)f2bf(o[f][3]) << 16);
    op[((size_t)b * 32 + f) * 512 + tid] = v;
  }
}

// ---------- combine 8 split-K partials (f-major bf16) -> f32 out ----------
__global__ void k_combine(const unsigned short* __restrict__ Opart,
                          const float* __restrict__ mpart, const float* __restrict__ lpart,
                          float* __restrict__ out) {
  int q = blockIdx.x;                 // 0..63 (128-row tile)
  int half = blockIdx.y;              // 0..1
  int tid = threadIdx.x;              // 512 threads
  int wave = tid >> 6, l4 = (tid >> 4) & 3, l15 = tid & 15;
  int row0 = q * 128 + wave * 16 + l4 * 4;

  float w[8][4], inv[4];
#pragma unroll
  for (int r = 0; r < 4; r++) {
    float M = NEGF;
    float mv[8];
#pragma unroll
    for (int s = 0; s < 8; s++) { mv[s] = mpart[s * 8192 + row0 + r]; M = fmaxf(M, mv[s]); }
    float L = 0.f;
#pragma unroll
    for (int s = 0; s < 8; s++) {
      float ws = __expf(mv[s] - M);
      w[s][r] = ws;
      L += ws * lpart[s * 8192 + row0 + r];
    }
    inv[r] = 1.0f / L;
  }
  const uint2* op = (const uint2*)Opart;
#pragma unroll
  for (int fo = 0; fo < 16; fo++) {
    int f = half * 16 + fo;
    float acc[4] = {0.f, 0.f, 0.f, 0.f};
#pragma unroll
    for (int s = 0; s < 8; s++) {
      uint2 v = op[((size_t)(q * 8 + s) * 32 + f) * 512 + tid];
      acc[0] += w[s][0] * bf2f((unsigned short)(v.x & 0xFFFFu));
      acc[1] += w[s][1] * bf2f((unsigned short)(v.x >> 16));
      acc[2] += w[s][2] * bf2f((unsigned short)(v.y & 0xFFFFu));
      acc[3] += w[s][3] * bf2f((unsigned short)(v.y >> 16));
    }
    int col = f * 16 + l15;
#pragma unroll
    for (int r = 0; r < 4; r++)
      out[(size_t)(row0 + r) * 512 + col] = acc[r] * inv[r];
  }
}

extern "C" void kernel_launch(void* const* d_in, const int* in_sizes, int n_in,
                              void* d_out, int out_size, void* d_ws, size_t ws_size,
                              hipStream_t stream) {
  const void* Q   = d_in[0];
  const void* K   = d_in[1];
  const void* V   = d_in[2];
  const void* WQw = d_in[3];
  const void* WQb = d_in[4];
  const void* WKw = d_in[5];
  const void* WKb = d_in[6];
  const void* mask = d_in[7];
  float* out = (float*)d_out;
  char* ws = (char*)d_ws;
  (void)in_sizes; (void)n_in; (void)out_size; (void)ws_size;

  constexpr size_t SZ_MAT = (size_t)8192 * 512 * 2;  // 8 MB bf16
  size_t off = 4096;
  unsigned short* Qb  = (unsigned short*)(ws + off); off += SZ_MAT;
  unsigned short* Kb  = (unsigned short*)(ws + off); off += SZ_MAT;
  unsigned short* Wqb = (unsigned short*)(ws + off); off += (size_t)512 * 512 * 2;
  unsigned short* Wkb = (unsigned short*)(ws + off); off += (size_t)512 * 512 * 2;
  unsigned short* bqb = (unsigned short*)(ws + off); off += 1024;
  unsigned short* bkb = (unsigned short*)(ws + off); off += 1024;
  unsigned short* Vt  = (unsigned short*)(ws + off); off += SZ_MAT;
  unsigned short* Qp  = (unsigned short*)(ws + off); off += SZ_MAT;
  unsigned short* Kp  = (unsigned short*)(ws + off); off += SZ_MAT;
  unsigned long long* mbits = (unsigned long long*)(ws + off); off += (size_t)8192 * 128 * 8;
  unsigned short* Opart = (unsigned short*)(ws + off); off += (size_t)512 * 512 * 32 * 8;  // 64 MB
  float* mpart = (float*)(ws + off); off += (size_t)8 * 8192 * 4;
  float* lpart = (float*)(ws + off); off += (size_t)8 * 8192 * 4;
  int* fflag = (int*)ws;
  int* esize = (int*)(ws + 64);

  k_detect<<<2, 64, 0, stream>>>((const unsigned int*)Q, (const unsigned int*)mask, fflag, esize);
  k_prep<<<4354, 256, 0, stream>>>(Q, Qb, K, Kb, WQw, Wqb, WKw, Wkb, WQb, bqb, WKb, bkb, fflag);
  k_transpose_v<<<dim3(128, 8), 256, 0, stream>>>(V, fflag, Vt);
  k_pack<<<1024, 256, 0, stream>>>(mask, esize, mbits);
  k_proj<<<dim3(64, 4, 2), 256, 0, stream>>>(Qb, Wqb, bqb, Qp, Kb, Wkb, bkb, Kp);
  k_attn<<<512, 512, 0, stream>>>(Qp, Kp, Vt, mbits, Opart, mpart, lpart);
  k_combine<<<dim3(64, 2), 512, 0, stream>>>(Opart, mpart, lpart, out);
}